// Round 12
// baseline (791.513 us; speedup 1.0000x reference)
//
#include <hip/hip_runtime.h>
#include <hip/hip_cooperative_groups.h>
#include <math.h>
#include <stdint.h>

namespace cg = cooperative_groups;

// ==================== bf16 hi/lo split helpers ====================

__device__ __forceinline__ uint16_t bf16r(float x) {
  uint32_t u = __float_as_uint(x);
  return (uint16_t)((u + 0x7FFFu + ((u >> 16) & 1u)) >> 16);
}
__device__ __forceinline__ void bfsplit(float x, uint16_t& h, uint16_t& l) {
  h = bf16r(x);
  float hf = __uint_as_float((uint32_t)h << 16);
  l = bf16r(x - hf);
}
__device__ __forceinline__ void store4split(uint16_t* oh, uint16_t* ol, float4 v) {
  ushort4 h, l;
  bfsplit(v.x, h.x, l.x); bfsplit(v.y, h.y, l.y);
  bfsplit(v.z, h.z, l.z); bfsplit(v.w, h.w, l.w);
  *reinterpret_cast<ushort4*>(oh) = h;
  *reinterpret_cast<ushort4*>(ol) = l;
}

// async 16B global -> LDS (DMA, no VGPR round-trip). LDS dest base is
// wave-uniform; HW adds lane*16. Global src is per-lane.
__device__ __forceinline__ void gload16(const uint16_t* g, uint16_t* l) {
  __builtin_amdgcn_global_load_lds(
      (const __attribute__((address_space(1))) uint32_t*)g,
      (__attribute__((address_space(3))) uint32_t*)l, 16, 0, 0);
}

using bf16x8 = __attribute__((ext_vector_type(8))) short;  // 8 bf16 (4 VGPRs)
using f32x4  = __attribute__((ext_vector_type(4))) float;  // MFMA accumulator

// ==================== COOPERATIVE FRONT-END (1 launch replaces 5) ====================
// Round-11 audit: components sum to ~180us vs 324 total with 12 launches ->
// ~12us/launch serialization dominates. This kernel fuses {prep, count, scan,
// scatter, attcoef1} with grid.sync() between dependent phases. Phase bodies
// are the round-11 verified kernels, re-indexed grid-stride. 512 blocks x 256
// threads (2 blocks/CU co-resident, 17KB LDS).

struct FrontArgs {
  const float *W_ih, *b_ih, *b_hh, *W1, *as1, *ad1, *W2, *as2, *ad2;
  const float* x;
  const int *src, *dst;
  int* degwp;  // deg[N] + wp[N]
  uint16_t *Wtbh, *Wtbl, *Bt1h, *Bt1l, *Bt2h, *Bt2l;
  float *bsum, *watt1, *watt2;
  float *a_s1, *a_d1;
  int *rowptr, *col, *csum, *choff;
  int N, E, prep_total;
};

__global__ __launch_bounds__(256, 2) void fused_front(FrontArgs a) {
  cg::grid_group grid = cg::this_grid();
  __shared__ float s_rows[16 * 128];
  __shared__ float s_wbuf[128 * 16];
  __shared__ int s_scan[256];
  const int tid = threadIdx.x;
  const int gsz = gridDim.x * 256;
  const int gidx = blockIdx.x * 256 + tid;
  const int n2 = 2 * a.N;

  // ---------- P0: zero deg/wp + prep weight planes / watt tables ----------
  for (int idx = gidx; idx < a.prep_total; idx += gsz) {
    if (idx < n2) { a.degwp[idx] = 0; continue; }
    int t = idx - n2;
    if (t < 98304) {  // Wtb: t = jp*512 + k (packed i,g,o of W_ih)
      int jp = t >> 9, k = t & 511;
      int j = (jp < 64) ? jp : jp + 64;
      uint16_t h, l;
      bfsplit(a.W_ih[(size_t)j * 512 + k], h, l);
      a.Wtbh[t] = h; a.Wtbl[t] = l;
      continue;
    }
    t -= 98304;
    if (t < 65536) {  // Bt1: t = n*128 + k  (W1^T)
      int n = t >> 7, k = t & 127;
      uint16_t h, l;
      bfsplit(a.W1[(size_t)k * 512 + n], h, l);
      a.Bt1h[t] = h; a.Bt1l[t] = l;
      continue;
    }
    t -= 65536;
    if (t < 32768) {  // Bt2: t = n*64 + k  (W2^T)
      int n = t >> 6, k = t & 63;
      uint16_t h, l;
      bfsplit(a.W2[(size_t)k * 512 + n], h, l);
      a.Bt2h[t] = h; a.Bt2l[t] = l;
      continue;
    }
    t -= 32768;
    if (t < 192) {
      int j = (t < 64) ? t : t + 64;
      a.bsum[t] = a.b_ih[j] + a.b_hh[j];
      continue;
    }
    t -= 192;
    if (t < 2048) {
      int f = t >> 4, c = t & 15;
      int k = c & 7;
      const float* att = ((c < 8) ? a.as1 : a.ad1) + k * 64;
      const float* w = a.W1 + (size_t)f * 512 + k * 64;
      float s = 0.f;
#pragma unroll
      for (int j = 0; j < 64; ++j) s = fmaf(w[j], att[j], s);
      a.watt1[t] = s;
      continue;
    }
    t -= 2048;
    if (t < 1024) {
      int f = t >> 4, c = t & 15;
      int k = c & 7;
      const float* att = ((c < 8) ? a.as2 : a.ad2) + k * 64;
      const float* w = a.W2 + (size_t)f * 512 + k * 64;
      float s = 0.f;
#pragma unroll
      for (int j = 0; j < 64; ++j) s = fmaf(w[j], att[j], s);
      a.watt2[t] = s;
    }
  }
  __threadfence();
  grid.sync();

  // ---------- P1: degree count + attcoef1 (independent, same phase) ----------
  for (int i = gidx; i < a.E; i += gsz) atomicAdd(&a.degwp[a.dst[i]], 1);
  {
    // watt1 -> LDS once (written in P0, visible after grid.sync)
    for (int i = tid; i < 512; i += 256)
      reinterpret_cast<float4*>(s_wbuf)[i] =
          reinterpret_cast<const float4*>(a.watt1)[i];
    const int nb16 = (a.N + 15) / 16;
    for (int vb = blockIdx.x; vb < nb16; vb += gridDim.x) {
      const int n0 = vb * 16;
      if (n0 + 16 <= a.N) {
        const float4* g = reinterpret_cast<const float4*>(a.x + (size_t)n0 * 128);
        float4* l = reinterpret_cast<float4*>(s_rows);
        for (int i = tid; i < 512; i += 256) l[i] = g[i];
      } else {
        for (int i = tid; i < 16 * 128; i += 256) {
          int r = i >> 7;
          s_rows[i] = (n0 + r < a.N) ? a.x[(size_t)(n0 + r) * 128 + (i & 127)] : 0.f;
        }
      }
      __syncthreads();
      const int local = tid >> 4, c = tid & 15;
      float s = 0.f;
#pragma unroll 8
      for (int f = 0; f < 128; ++f) s = fmaf(s_rows[local * 128 + f], s_wbuf[f * 16 + c], s);
      const int node = n0 + local;
      if (node < a.N) {
        if (c < 8) a.a_s1[(size_t)node * 8 + c] = s;
        else       a.a_d1[(size_t)node * 8 + (c - 8)] = s;
      }
      __syncthreads();  // WAR on s_rows before next vb
    }
  }
  __threadfence();
  grid.sync();

  // ---------- P2: per-chunk (256 nodes) exclusive scan of deg+1 ----------
  const int NCH = (a.N + 255) / 256;
  for (int vb = blockIdx.x; vb < NCH; vb += gridDim.x) {
    int i = vb * 256 + tid;
    int val = (i < a.N) ? (a.degwp[i] + 1) : 0;
    int incl = val;
    s_scan[tid] = incl;
    __syncthreads();
    for (int s = 1; s < 256; s <<= 1) {
      int t = (tid >= s) ? s_scan[tid - s] : 0;
      __syncthreads();
      incl += t;
      s_scan[tid] = incl;
      __syncthreads();
    }
    if (i < a.N) a.rowptr[i] = incl - val;
    if (tid == 255) a.csum[vb] = incl;
    __syncthreads();
  }
  __threadfence();
  grid.sync();

  // ---------- P3: scan chunk totals (block 0; NCH <= 256) ----------
  if (blockIdx.x == 0) {
    int val = (tid < NCH) ? a.csum[tid] : 0;
    int incl = val;
    s_scan[tid] = incl;
    __syncthreads();
    for (int s = 1; s < 256; s <<= 1) {
      int t = (tid >= s) ? s_scan[tid - s] : 0;
      __syncthreads();
      incl += t;
      s_scan[tid] = incl;
      __syncthreads();
    }
    if (tid < NCH) a.choff[tid] = incl - val;
    if (tid == NCH - 1) a.rowptr[a.N] = incl;
  }
  __threadfence();
  grid.sync();

  // ---------- P4: add chunk offsets ----------
  for (int i = gidx; i < a.N; i += gsz) a.rowptr[i] += a.choff[i >> 8];
  __threadfence();
  grid.sync();

  // ---------- P5: scatter (edges + self-loops) ----------
  int* wp = a.degwp + a.N;
  for (int i = gidx; i < a.E + a.N; i += gsz) {
    if (i < a.E) {
      int d = a.dst[i];
      int p = a.rowptr[d] + atomicAdd(&wp[d], 1);
      a.col[p] = a.src[i];
    } else {
      int d = i - a.E;
      int p = a.rowptr[d] + atomicAdd(&wp[d], 1);
      a.col[p] = d;
    }
  }
}

// ==================== MFMA split-bf16 GEMM (async-DMA staged) ====================
// C = A @ B (+bias), fp32-precision via hi/lo bf16 split:
//   C = Ah*Bh + Al*Bh + Ah*Bl   (Al*Bl ~ 2^-18 dropped)
// A and B are pre-split bf16 planes, [rows][K]. global_load_lds staging
// (LDS dest linear, global src pre-swizzled chunk c^(row&7)); 2-phase
// pipeline. Verified rounds 3-11.

template <bool SPLIT_OUT>
__global__ __launch_bounds__(256) void gemm_mfma(
    const uint16_t* __restrict__ Ah, const uint16_t* __restrict__ Al,
    const uint16_t* __restrict__ Bh, const uint16_t* __restrict__ Bl,
    float* __restrict__ C, uint16_t* __restrict__ Ch, uint16_t* __restrict__ Cl,
    const float* __restrict__ bias,
    int M, int K, int lda, int aZ, int bZ, int ldc, int cZ, int biasZ) {
  constexpr int BM = 64, BN = 64, BK = 64;
  constexpr int PL = BM * BK;  // elements per plane per buffer
  __shared__ __align__(16) uint16_t sAh[2 * PL], sAl[2 * PL];
  __shared__ __align__(16) uint16_t sBh[2 * PL], sBl[2 * PL];
  const int z = blockIdx.z;
  Ah += (size_t)z * aZ; Al += (size_t)z * aZ;
  Bh += (size_t)z * bZ; Bl += (size_t)z * bZ;
  const int tid = threadIdx.x;
  const int wid = tid >> 6, lane = tid & 63;
  // ---- bijective XCD swizzle over (x,y) ----
  int L = blockIdx.x + gridDim.x * blockIdx.y;
  int nwg = gridDim.x * gridDim.y;
  int q = nwg >> 3, r = nwg & 7;
  int xcd = L & 7, gix = L >> 3;
  int base = (xcd < r) ? xcd * (q + 1) : r * (q + 1) + (xcd - r) * q;
  int w = base + gix;
  const int bm = (w / gridDim.x) * BM;
  const int bn = (w % gridDim.x) * BN;
  const int fr = lane & 15;   // row-in-frag (A) / col-in-frag (B,C)
  const int kg = lane >> 4;   // k-group (8 consecutive k each)
  const int mbase = wid * 16;
  f32x4 acc[4] = {};

  auto stage = [&](int sb, int k0) {
#pragma unroll
    for (int j = 0; j < 2; ++j) {
      int idx = (wid * 2 + j) * 64 + lane;
      int row = idx >> 3, c = idx & 7;
      int rg = min(bm + row, M - 1);
      size_t goA = (size_t)rg * lda + k0 + ((c ^ (row & 7)) << 3);
      gload16(Ah + goA, sAh + sb * PL + (wid * 2 + j) * 512);
      gload16(Al + goA, sAl + sb * PL + (wid * 2 + j) * 512);
      size_t goB = (size_t)(bn + row) * K + k0 + ((c ^ (row & 7)) << 3);
      gload16(Bh + goB, sBh + sb * PL + (wid * 2 + j) * 512);
      gload16(Bl + goB, sBl + sb * PL + (wid * 2 + j) * 512);
    }
  };

  stage(0, 0);
  __syncthreads();  // drains vmcnt: tile 0 resident
  int buf = 0;
  for (int k0 = 0; k0 < K; k0 += BK) {
    const bool more = (k0 + BK) < K;
    if (more) stage(buf ^ 1, k0 + BK);  // async; flies during MFMA phase
    const char* pAh = (const char*)sAh + buf * (PL * 2);
    const char* pAl = (const char*)sAl + buf * (PL * 2);
    const char* pBh = (const char*)sBh + buf * (PL * 2);
    const char* pBl = (const char*)sBl + buf * (PL * 2);
#pragma unroll
    for (int ks = 0; ks < 2; ++ks) {
      const int kc = ks * 4 + kg;
      bf16x8 ah, al, bh[4], bl[4];
      {
        int m = mbase + fr;
        int off = m * 128 + ((kc ^ (m & 7)) << 4);
        ah = *reinterpret_cast<const bf16x8*>(pAh + off);
        al = *reinterpret_cast<const bf16x8*>(pAl + off);
      }
#pragma unroll
      for (int j = 0; j < 4; ++j) {
        int n = j * 16 + fr;
        int off = n * 128 + ((kc ^ (n & 7)) << 4);
        bh[j] = *reinterpret_cast<const bf16x8*>(pBh + off);
        bl[j] = *reinterpret_cast<const bf16x8*>(pBl + off);
      }
#pragma unroll
      for (int j = 0; j < 4; ++j) {
        acc[j] = __builtin_amdgcn_mfma_f32_16x16x32_bf16(ah, bh[j], acc[j], 0, 0, 0);
        acc[j] = __builtin_amdgcn_mfma_f32_16x16x32_bf16(al, bh[j], acc[j], 0, 0, 0);
        acc[j] = __builtin_amdgcn_mfma_f32_16x16x32_bf16(ah, bl[j], acc[j], 0, 0, 0);
      }
    }
    if (more) {
      __syncthreads();  // drains prefetch vmcnt + releases buf
      buf ^= 1;
    }
  }
  float bz[4];
#pragma unroll
  for (int j = 0; j < 4; ++j)
    bz[j] = bias ? bias[(size_t)z * biasZ + bn + j * 16 + fr] : 0.f;
  if (SPLIT_OUT) {
    Ch += (size_t)z * cZ;
    Cl += (size_t)z * cZ;
  } else {
    C += (size_t)z * cZ;
  }
  {
    int mr = bm + mbase + kg * 4;
#pragma unroll
    for (int rr = 0; rr < 4; ++rr) {
      int m = mr + rr;
      if (m < M) {
#pragma unroll
        for (int j = 0; j < 4; ++j) {
          float v = acc[j][rr] + bz[j];
          size_t o = (size_t)m * ldc + bn + j * 16 + fr;
          if (SPLIT_OUT) {
            uint16_t h, l;
            bfsplit(v, h, l);
            Ch[o] = h; Cl[o] = l;
          } else {
            C[o] = v;
          }
        }
      }
    }
  }
}

// ==================== GAT pre-aggregation: one WAVE per dst node ====================
// ROUND-3 implementation (fastest measured across 5 variants). Two passes:
// denominator pass (a_s gathers L2-resident), then aggregate pass staging
// alpha in per-wave LDS chunks of 8 edges. Emits hi/lo bf16 planes.

template <int F>
__global__ __launch_bounds__(256) void gat_aggregate_wave(
    const float* __restrict__ feat, const float* __restrict__ a_s,
    const float* __restrict__ a_d, const int* __restrict__ rowptr,
    const int* __restrict__ col, uint16_t* __restrict__ aggH,
    uint16_t* __restrict__ aggL, int n) {
  constexpr int F4 = F / 4;
  constexpr int HPG = (F == 128) ? 4 : 2;
  __shared__ float s_alpha[4][8][8];
  __shared__ int s_cols[4][8];
  const int wid = threadIdx.x >> 6;
  const int lane = threadIdx.x & 63;
  const int node = blockIdx.x * 4 + wid;
  if (node >= n) return;
  const int start = rowptr[node];
  const int deg = rowptr[node + 1] - start;
  const int j = lane >> 3;
  const int h = lane & 7;
  const float adh = a_d[(size_t)node * 8 + h];
  float den = 0.f;
  for (int e = j; e < deg; e += 8) {
    int s = col[start + e];
    float v = a_s[(size_t)s * 8 + h] + adh;
    v = (v > 0.f) ? v : 0.2f * v;
    den += __expf(v);
  }
  den += __shfl_xor(den, 8);
  den += __shfl_xor(den, 16);
  den += __shfl_xor(den, 32);
  const float inv = 1.f / (den + 1e-16f);
  const int f4 = lane & (F4 - 1);
  const int hbase = (lane / F4) * HPG;
  float4 acc0 = make_float4(0.f, 0.f, 0.f, 0.f);
  float4 acc1 = make_float4(0.f, 0.f, 0.f, 0.f);
  float4 acc2 = make_float4(0.f, 0.f, 0.f, 0.f);
  float4 acc3 = make_float4(0.f, 0.f, 0.f, 0.f);
  for (int c0 = 0; c0 < deg; c0 += 8) {
    float aval = 0.f;
    int sj = 0;
    if (c0 + j < deg) {
      sj = col[start + c0 + j];
      float v = a_s[(size_t)sj * 8 + h] + adh;
      v = (v > 0.f) ? v : 0.2f * v;
      aval = __expf(v) * inv;
    }
    s_alpha[wid][j][h] = aval;
    if (h == 0) s_cols[wid][j] = sj;
    __builtin_amdgcn_wave_barrier();
    const int ce = min(8, deg - c0);
    for (int e = 0; e < ce; ++e) {
      int s = s_cols[wid][e];
      float4 fv = *reinterpret_cast<const float4*>(feat + (size_t)s * F + f4 * 4);
      if constexpr (HPG == 4) {
        float4 al = *reinterpret_cast<const float4*>(&s_alpha[wid][e][hbase]);
        acc0.x = fmaf(al.x, fv.x, acc0.x); acc0.y = fmaf(al.x, fv.y, acc0.y);
        acc0.z = fmaf(al.x, fv.z, acc0.z); acc0.w = fmaf(al.x, fv.w, acc0.w);
        acc1.x = fmaf(al.y, fv.x, acc1.x); acc1.y = fmaf(al.y, fv.y, acc1.y);
        acc1.z = fmaf(al.y, fv.z, acc1.z); acc1.w = fmaf(al.y, fv.w, acc1.w);
        acc2.x = fmaf(al.z, fv.x, acc2.x); acc2.y = fmaf(al.z, fv.y, acc2.y);
        acc2.z = fmaf(al.z, fv.z, acc2.z); acc2.w = fmaf(al.z, fv.w, acc2.w);
        acc3.x = fmaf(al.w, fv.x, acc3.x); acc3.y = fmaf(al.w, fv.y, acc3.y);
        acc3.z = fmaf(al.w, fv.z, acc3.z); acc3.w = fmaf(al.w, fv.w, acc3.w);
      } else {
        float2 al = *reinterpret_cast<const float2*>(&s_alpha[wid][e][hbase]);
        acc0.x = fmaf(al.x, fv.x, acc0.x); acc0.y = fmaf(al.x, fv.y, acc0.y);
        acc0.z = fmaf(al.x, fv.z, acc0.z); acc0.w = fmaf(al.x, fv.w, acc0.w);
        acc1.x = fmaf(al.y, fv.x, acc1.x); acc1.y = fmaf(al.y, fv.y, acc1.y);
        acc1.z = fmaf(al.y, fv.z, acc1.z); acc1.w = fmaf(al.y, fv.w, acc1.w);
      }
    }
    __builtin_amdgcn_wave_barrier();
  }
  size_t basep = (size_t)node * 8 * F + (size_t)hbase * F + f4 * 4;
  store4split(aggH + basep, aggL + basep, acc0);
  store4split(aggH + basep + F, aggL + basep + F, acc1);
  if constexpr (HPG == 4) {
    store4split(aggH + basep + 2 * F, aggL + basep + 2 * F, acc2);
    store4split(aggH + basep + 3 * F, aggL + basep + 3 * F, acc3);
  }
}

// ==================== fused LSTM activation + attcoef2 ====================

__global__ __launch_bounds__(256) void lstm_act_attcoef_kernel(
    const float* __restrict__ gates, const float* __restrict__ bsum,
    const float* __restrict__ watt2, float* __restrict__ h2,
    float* __restrict__ a_s2, float* __restrict__ a_d2, int n) {
  __shared__ float h2t[4][64];
  __shared__ float wbuf[64 * 16];
  const int tid = threadIdx.x;
  reinterpret_cast<float4*>(wbuf)[tid] = reinterpret_cast<const float4*>(watt2)[tid];
  const int nl = tid >> 6, j = tid & 63;
  const int node = blockIdx.x * 4 + nl;
  float hv = 0.f;
  if (node < n) {
    const float* g0 = gates + (size_t)node * 192;
    float iv = g0[j] + bsum[j];
    float gv = g0[64 + j] + bsum[64 + j];
    float ov = g0[128 + j] + bsum[128 + j];
    float c = (1.f / (1.f + __expf(-iv))) * tanhf(gv);
    hv = fmaxf((1.f / (1.f + __expf(-ov))) * tanhf(c), 0.f);
    h2[(size_t)node * 64 + j] = hv;
  }
  h2t[nl][j] = hv;
  __syncthreads();
  if (j < 16 && node < n) {
    float s = 0.f;
#pragma unroll 16
    for (int f = 0; f < 64; ++f) s = fmaf(h2t[nl][f], wbuf[f * 16 + j], s);
    if (j < 8) a_s2[(size_t)node * 8 + j] = s;
    else       a_d2[(size_t)node * 8 + (j - 8)] = s;
  }
}

// ==================== final row softmax: one WAVE per node ====================

__global__ __launch_bounds__(256) void softmax512_wave(const float* __restrict__ in,
                                                       float* __restrict__ out, int n) {
  const int wid = threadIdx.x >> 6, lane = threadIdx.x & 63;
  const int node = blockIdx.x * 4 + wid;
  if (node >= n) return;
  const float4* ip = reinterpret_cast<const float4*>(in + (size_t)node * 512);
  float4 v0 = ip[lane];
  float4 v1 = ip[64 + lane];
  float m = fmaxf(fmaxf(fmaxf(v0.x, v0.y), fmaxf(v0.z, v0.w)),
                  fmaxf(fmaxf(v1.x, v1.y), fmaxf(v1.z, v1.w)));
#pragma unroll
  for (int d = 1; d < 64; d <<= 1) m = fmaxf(m, __shfl_xor(m, d));
  float4 e0, e1;
  e0.x = __expf(v0.x - m); e0.y = __expf(v0.y - m);
  e0.z = __expf(v0.z - m); e0.w = __expf(v0.w - m);
  e1.x = __expf(v1.x - m); e1.y = __expf(v1.y - m);
  e1.z = __expf(v1.z - m); e1.w = __expf(v1.w - m);
  float s = e0.x + e0.y + e0.z + e0.w + e1.x + e1.y + e1.z + e1.w;
#pragma unroll
  for (int d = 1; d < 64; d <<= 1) s += __shfl_xor(s, d);
  float inv = 1.f / s;
  e0.x *= inv; e0.y *= inv; e0.z *= inv; e0.w *= inv;
  e1.x *= inv; e1.y *= inv; e1.z *= inv; e1.w *= inv;
  float4* op = reinterpret_cast<float4*>(out + (size_t)node * 512);
  op[lane] = e0;
  op[64 + lane] = e1;
}

// ============================ launch ============================

extern "C" void kernel_launch(void* const* d_in, const int* in_sizes, int n_in,
                              void* d_out, int out_size, void* d_ws, size_t ws_size,
                              hipStream_t stream) {
  const float* x      = (const float*)d_in[0];
  const int*   ei     = (const int*)d_in[1];
  const float* W1     = (const float*)d_in[3];
  const float* att_s1 = (const float*)d_in[4];
  const float* att_d1 = (const float*)d_in[5];
  const float* bias1  = (const float*)d_in[6];
  const float* W_ih   = (const float*)d_in[7];
  const float* b_ih   = (const float*)d_in[9];
  const float* b_hh   = (const float*)d_in[10];
  const float* W2     = (const float*)d_in[11];
  const float* att_s2 = (const float*)d_in[12];
  const float* att_d2 = (const float*)d_in[13];
  const float* bias2  = (const float*)d_in[14];
  float* out = (float*)d_out;

  const int N = in_sizes[0] / 128;
  const int E = in_sizes[1] / 2;
  const int* src = ei;
  const int* dst = ei + E;

  char* p = (char*)d_ws;
  auto alloc = [&](size_t bytes) {
    char* r = p;
    p += (bytes + 255) & ~(size_t)255;
    return r;
  };
  char* slotA = alloc((size_t)N * 4096);  // agg1 planes; later gates2+h2+agg2 planes
  char* slotB = alloc((size_t)N * 2048);  // g1 planes; later h3p
  float* a_s1 = (float*)alloc((size_t)N * 8 * 4);
  float* a_d1 = (float*)alloc((size_t)N * 8 * 4);
  float* a_s2 = (float*)alloc((size_t)N * 8 * 4);
  float* a_d2 = (float*)alloc((size_t)N * 8 * 4);
  float* watt1 = (float*)alloc(128 * 16 * 4);
  float* watt2 = (float*)alloc(64 * 16 * 4);
  uint16_t* Wtbh = (uint16_t*)alloc((size_t)192 * 512 * 2);
  uint16_t* Wtbl = (uint16_t*)alloc((size_t)192 * 512 * 2);
  uint16_t* Bt1h = (uint16_t*)alloc((size_t)512 * 128 * 2);
  uint16_t* Bt1l = (uint16_t*)alloc((size_t)512 * 128 * 2);
  uint16_t* Bt2h = (uint16_t*)alloc((size_t)512 * 64 * 2);
  uint16_t* Bt2l = (uint16_t*)alloc((size_t)512 * 64 * 2);
  float* bsum = (float*)alloc(192 * 4);
  int* deg    = (int*)alloc((size_t)2 * N * 4);  // deg + wp adjacent
  int* rowptr = (int*)alloc((size_t)(N + 1) * 4);
  int* col    = (int*)alloc((size_t)(E + N) * 4);
  int* csum   = (int*)alloc(256 * 4);
  int* choff  = (int*)alloc(256 * 4);

  // slotA phase 1: agg1 hi/lo planes [N,1024] bf16 each
  uint16_t* agg1h = (uint16_t*)slotA;
  uint16_t* agg1l = agg1h + (size_t)N * 1024;
  // slotA phase 2 (agg1 dead after proj1): gates2 [N,192] f32, h2 [N,64] f32,
  // agg2 hi/lo planes [N,512] bf16 each  (768 + 256 + 1024 + 1024 <= 4096 B/node)
  float* gates2 = (float*)slotA;
  float* h2 = (float*)(slotA + (size_t)N * 768);
  uint16_t* agg2h = (uint16_t*)(slotA + (size_t)N * 1024);
  uint16_t* agg2l = agg2h + (size_t)N * 512;
  // slotB phase 1: g1 hi/lo planes [N,512] bf16 each; phase 2: h3p [N,512] f32
  uint16_t* g1h = (uint16_t*)slotB;
  uint16_t* g1l = g1h + (size_t)N * 512;
  float* h3p = (float*)slotB;

  // ---- cooperative front-end: prep + CSR build + attcoef1 (1 launch) ----
  {
    FrontArgs fa;
    fa.W_ih = W_ih; fa.b_ih = b_ih; fa.b_hh = b_hh; fa.W1 = W1;
    fa.as1 = att_s1; fa.ad1 = att_d1; fa.W2 = W2; fa.as2 = att_s2; fa.ad2 = att_d2;
    fa.x = x; fa.src = src; fa.dst = dst;
    fa.degwp = deg;
    fa.Wtbh = Wtbh; fa.Wtbl = Wtbl; fa.Bt1h = Bt1h; fa.Bt1l = Bt1l;
    fa.Bt2h = Bt2h; fa.Bt2l = Bt2l;
    fa.bsum = bsum; fa.watt1 = watt1; fa.watt2 = watt2;
    fa.a_s1 = a_s1; fa.a_d1 = a_d1;
    fa.rowptr = rowptr; fa.col = col; fa.csum = csum; fa.choff = choff;
    fa.N = N; fa.E = E;
    fa.prep_total = 2 * N + 98304 + 65536 + 32768 + 192 + 2048 + 1024;
    void* kargs[] = {&fa};
    hipLaunchCooperativeKernel((const void*)fused_front, dim3(512), dim3(256),
                               kargs, 0, stream);
  }

  const int NYB = (N + 63) / 64;

  // ---- GATConv1: aggregate x (emit split planes), project ----
  gat_aggregate_wave<128><<<(N + 3) / 4, 256, 0, stream>>>(x, a_s1, a_d1, rowptr, col,
                                                           agg1h, agg1l, N);
  {
    dim3 g(1, NYB, 8);
    gemm_mfma<true><<<g, 256, 0, stream>>>(
        agg1h, agg1l, Bt1h, Bt1l, nullptr, g1h, g1l, bias1,
        N, 128, /*lda*/1024, /*aZ*/128, /*bZ*/64 * 128, /*ldc*/512, /*cZ*/64, /*biasZ*/64);
  }

  // ---- LSTM gates GEMM + fused act/attcoef2 ----
  {
    dim3 g(3, NYB, 1);
    gemm_mfma<false><<<g, 256, 0, stream>>>(
        g1h, g1l, Wtbh, Wtbl, gates2, nullptr, nullptr, nullptr,
        N, 512, /*lda*/512, 0, 0, /*ldc*/192, 0, 0);
  }
  lstm_act_attcoef_kernel<<<(N + 3) / 4, 256, 0, stream>>>(gates2, bsum, watt2,
                                                           h2, a_s2, a_d2, N);

  // ---- GATConv2: aggregate h2 (emit split planes), project, row softmax ----
  gat_aggregate_wave<64><<<(N + 3) / 4, 256, 0, stream>>>(h2, a_s2, a_d2, rowptr, col,
                                                          agg2h, agg2l, N);
  {
    dim3 g(1, NYB, 8);
    gemm_mfma<false><<<g, 256, 0, stream>>>(
        agg2h, agg2l, Bt2h, Bt2l, h3p, nullptr, nullptr, bias2,
        N, 64, /*lda*/512, /*aZ*/64, /*bZ*/64 * 64, /*ldc*/512, /*cZ*/64, /*biasZ*/64);
  }
  softmax512_wave<<<(N + 3) / 4, 256, 0, stream>>>(h3p, out, N);
}

// Round 13
// 323.750 us; speedup vs baseline: 2.4448x; 2.4448x over previous
//
#include <hip/hip_runtime.h>
#include <math.h>
#include <stdint.h>

// ============================ CSR build ============================

// exclusive scan of (deg[i]+1) (+1 = self loop); single block, single chunk,
// 20 vals/thread fully unrolled (fixed indices -> registers, no scratch).
__global__ void scan_kernel(const int* __restrict__ deg, int* __restrict__ rowptr, int n) {
  __shared__ int buf[1024];
  const int tid = threadIdx.x;
  const int i0 = tid * 20;
  int v[20];
  int tsum = 0;
#pragma unroll
  for (int k = 0; k < 20; ++k) {
    int i = i0 + k;
    v[k] = (i < n) ? (deg[i] + 1) : 0;
    tsum += v[k];
  }
  int incl = tsum;
  buf[tid] = incl;
  __syncthreads();
  for (int s = 1; s < 1024; s <<= 1) {
    int t = (tid >= (unsigned)s) ? buf[tid - s] : 0;
    __syncthreads();
    incl += t;
    buf[tid] = incl;
    __syncthreads();
  }
  int excl = incl - tsum;
#pragma unroll
  for (int k = 0; k < 20; ++k) {
    int i = i0 + k;
    if (i < n) rowptr[i] = excl;
    excl += v[k];
  }
  if (tid == 1023) rowptr[n] = incl;
}

__global__ void scatter_kernel(const int* __restrict__ src, const int* __restrict__ dst,
                               const int* __restrict__ rowptr, int* __restrict__ wp,
                               int* __restrict__ col, int E, int n) {
  int i = blockIdx.x * 256 + threadIdx.x;
  if (i < E) {
    int d = dst[i];
    int p = rowptr[d] + atomicAdd(&wp[d], 1);
    col[p] = src[i];
  } else if (i < E + n) {
    int d = i - E;
    int p = rowptr[d] + atomicAdd(&wp[d], 1);
    col[p] = d;
  }
}

// ==================== bf16 hi/lo split helpers ====================

__device__ __forceinline__ uint16_t bf16r(float x) {
  uint32_t u = __float_as_uint(x);
  return (uint16_t)((u + 0x7FFFu + ((u >> 16) & 1u)) >> 16);
}
__device__ __forceinline__ void bfsplit(float x, uint16_t& h, uint16_t& l) {
  h = bf16r(x);
  float hf = __uint_as_float((uint32_t)h << 16);
  l = bf16r(x - hf);
}
__device__ __forceinline__ void store4split(uint16_t* oh, uint16_t* ol, float4 v) {
  ushort4 h, l;
  bfsplit(v.x, h.x, l.x); bfsplit(v.y, h.y, l.y);
  bfsplit(v.z, h.z, l.z); bfsplit(v.w, h.w, l.w);
  *reinterpret_cast<ushort4*>(oh) = h;
  *reinterpret_cast<ushort4*>(ol) = l;
}

// async 16B global -> LDS (DMA, no VGPR round-trip). LDS dest base is
// wave-uniform; HW adds lane*16. Global src is per-lane.
__device__ __forceinline__ void gload16(const uint16_t* g, uint16_t* l) {
  __builtin_amdgcn_global_load_lds(
      (const __attribute__((address_space(1))) uint32_t*)g,
      (__attribute__((address_space(3))) uint32_t*)l, 16, 0, 0);
}

using bf16x8 = __attribute__((ext_vector_type(8))) short;  // 8 bf16 (4 VGPRs)
using f32x4  = __attribute__((ext_vector_type(4))) float;  // MFMA accumulator

// ==================== MFMA split-bf16 GEMM (async-DMA staged) ====================
// C = A @ B (+bias), fp32-precision via hi/lo bf16 split:
//   C = Ah*Bh + Al*Bh + Ah*Bl   (Al*Bl ~ 2^-18 dropped)
// A and B are pre-split bf16 planes, [rows][K]. global_load_lds staging
// (LDS dest linear, global src pre-swizzled chunk c^(row&7)); 2-phase
// pipeline. Verified rounds 3-11.

template <bool SPLIT_OUT>
__global__ __launch_bounds__(256) void gemm_mfma(
    const uint16_t* __restrict__ Ah, const uint16_t* __restrict__ Al,
    const uint16_t* __restrict__ Bh, const uint16_t* __restrict__ Bl,
    float* __restrict__ C, uint16_t* __restrict__ Ch, uint16_t* __restrict__ Cl,
    const float* __restrict__ bias,
    int M, int K, int lda, int aZ, int bZ, int ldc, int cZ, int biasZ) {
  constexpr int BM = 64, BN = 64, BK = 64;
  constexpr int PL = BM * BK;  // elements per plane per buffer
  __shared__ __align__(16) uint16_t sAh[2 * PL], sAl[2 * PL];
  __shared__ __align__(16) uint16_t sBh[2 * PL], sBl[2 * PL];
  const int z = blockIdx.z;
  Ah += (size_t)z * aZ; Al += (size_t)z * aZ;
  Bh += (size_t)z * bZ; Bl += (size_t)z * bZ;
  const int tid = threadIdx.x;
  const int wid = tid >> 6, lane = tid & 63;
  // ---- bijective XCD swizzle over (x,y) ----
  int L = blockIdx.x + gridDim.x * blockIdx.y;
  int nwg = gridDim.x * gridDim.y;
  int q = nwg >> 3, r = nwg & 7;
  int xcd = L & 7, gix = L >> 3;
  int base = (xcd < r) ? xcd * (q + 1) : r * (q + 1) + (xcd - r) * q;
  int w = base + gix;
  const int bm = (w / gridDim.x) * BM;
  const int bn = (w % gridDim.x) * BN;
  const int fr = lane & 15;   // row-in-frag (A) / col-in-frag (B,C)
  const int kg = lane >> 4;   // k-group (8 consecutive k each)
  const int mbase = wid * 16;
  f32x4 acc[4] = {};

  auto stage = [&](int sb, int k0) {
#pragma unroll
    for (int j = 0; j < 2; ++j) {
      int idx = (wid * 2 + j) * 64 + lane;
      int row = idx >> 3, c = idx & 7;
      int rg = min(bm + row, M - 1);
      size_t goA = (size_t)rg * lda + k0 + ((c ^ (row & 7)) << 3);
      gload16(Ah + goA, sAh + sb * PL + (wid * 2 + j) * 512);
      gload16(Al + goA, sAl + sb * PL + (wid * 2 + j) * 512);
      size_t goB = (size_t)(bn + row) * K + k0 + ((c ^ (row & 7)) << 3);
      gload16(Bh + goB, sBh + sb * PL + (wid * 2 + j) * 512);
      gload16(Bl + goB, sBl + sb * PL + (wid * 2 + j) * 512);
    }
  };

  stage(0, 0);
  __syncthreads();  // drains vmcnt: tile 0 resident
  int buf = 0;
  for (int k0 = 0; k0 < K; k0 += BK) {
    const bool more = (k0 + BK) < K;
    if (more) stage(buf ^ 1, k0 + BK);  // async; flies during MFMA phase
    const char* pAh = (const char*)sAh + buf * (PL * 2);
    const char* pAl = (const char*)sAl + buf * (PL * 2);
    const char* pBh = (const char*)sBh + buf * (PL * 2);
    const char* pBl = (const char*)sBl + buf * (PL * 2);
#pragma unroll
    for (int ks = 0; ks < 2; ++ks) {
      const int kc = ks * 4 + kg;
      bf16x8 ah, al, bh[4], bl[4];
      {
        int m = mbase + fr;
        int off = m * 128 + ((kc ^ (m & 7)) << 4);
        ah = *reinterpret_cast<const bf16x8*>(pAh + off);
        al = *reinterpret_cast<const bf16x8*>(pAl + off);
      }
#pragma unroll
      for (int j = 0; j < 4; ++j) {
        int n = j * 16 + fr;
        int off = n * 128 + ((kc ^ (n & 7)) << 4);
        bh[j] = *reinterpret_cast<const bf16x8*>(pBh + off);
        bl[j] = *reinterpret_cast<const bf16x8*>(pBl + off);
      }
#pragma unroll
      for (int j = 0; j < 4; ++j) {
        acc[j] = __builtin_amdgcn_mfma_f32_16x16x32_bf16(ah, bh[j], acc[j], 0, 0, 0);
        acc[j] = __builtin_amdgcn_mfma_f32_16x16x32_bf16(al, bh[j], acc[j], 0, 0, 0);
        acc[j] = __builtin_amdgcn_mfma_f32_16x16x32_bf16(ah, bl[j], acc[j], 0, 0, 0);
      }
    }
    if (more) {
      __syncthreads();  // drains prefetch vmcnt + releases buf
      buf ^= 1;
    }
  }
  float bz[4];
#pragma unroll
  for (int j = 0; j < 4; ++j)
    bz[j] = bias ? bias[(size_t)z * biasZ + bn + j * 16 + fr] : 0.f;
  if (SPLIT_OUT) {
    Ch += (size_t)z * cZ;
    Cl += (size_t)z * cZ;
  } else {
    C += (size_t)z * cZ;
  }
  {
    int mr = bm + mbase + kg * 4;
#pragma unroll
    for (int rr = 0; rr < 4; ++rr) {
      int m = mr + rr;
      if (m < M) {
#pragma unroll
        for (int j = 0; j < 4; ++j) {
          float v = acc[j][rr] + bz[j];
          size_t o = (size_t)m * ldc + bn + j * 16 + fr;
          if (SPLIT_OUT) {
            uint16_t h, l;
            bfsplit(v, h, l);
            Ch[o] = h; Cl[o] = l;
          } else {
            C[o] = v;
          }
        }
      }
    }
  }
}

// ==================== merged prep (one launch, also zeroes deg/wp) ====================

__global__ void prep_all_kernel(const float* __restrict__ W_ih, const float* __restrict__ b_ih,
                                const float* __restrict__ b_hh, const float* __restrict__ W1,
                                const float* __restrict__ as1, const float* __restrict__ ad1,
                                const float* __restrict__ W2, const float* __restrict__ as2,
                                const float* __restrict__ ad2,
                                int* __restrict__ degwp,
                                uint16_t* __restrict__ Wtbh, uint16_t* __restrict__ Wtbl,
                                uint16_t* __restrict__ Bt1h, uint16_t* __restrict__ Bt1l,
                                uint16_t* __restrict__ Bt2h, uint16_t* __restrict__ Bt2l,
                                float* __restrict__ bsum, float* __restrict__ watt1,
                                float* __restrict__ watt2, int n2) {
  int idx = blockIdx.x * 256 + threadIdx.x;
  if (idx < n2) {
    degwp[idx] = 0;
    return;
  }
  int t = idx - n2;
  if (t < 98304) {  // Wtb: t = jp*512 + k
    int jp = t >> 9, k = t & 511;
    int j = (jp < 64) ? jp : jp + 64;
    uint16_t h, l;
    bfsplit(W_ih[(size_t)j * 512 + k], h, l);
    Wtbh[t] = h; Wtbl[t] = l;
    return;
  }
  t -= 98304;
  if (t < 65536) {  // Bt1: t = n*128 + k
    int n = t >> 7, k = t & 127;
    uint16_t h, l;
    bfsplit(W1[(size_t)k * 512 + n], h, l);
    Bt1h[t] = h; Bt1l[t] = l;
    return;
  }
  t -= 65536;
  if (t < 32768) {  // Bt2: t = n*64 + k
    int n = t >> 6, k = t & 63;
    uint16_t h, l;
    bfsplit(W2[(size_t)k * 512 + n], h, l);
    Bt2h[t] = h; Bt2l[t] = l;
    return;
  }
  t -= 32768;
  if (t < 192) {
    int j = (t < 64) ? t : t + 64;
    bsum[t] = b_ih[j] + b_hh[j];
    return;
  }
  t -= 192;
  if (t < 2048) {
    int f = t >> 4, c = t & 15;
    int k = c & 7;
    const float* att = ((c < 8) ? as1 : ad1) + k * 64;
    const float* w = W1 + (size_t)f * 512 + k * 64;
    float s = 0.f;
#pragma unroll
    for (int j = 0; j < 64; ++j) s = fmaf(w[j], att[j], s);
    watt1[t] = s;
    return;
  }
  t -= 2048;
  if (t < 1024) {
    int f = t >> 4, c = t & 15;
    int k = c & 7;
    const float* att = ((c < 8) ? as2 : ad2) + k * 64;
    const float* w = W2 + (size_t)f * 512 + k * 64;
    float s = 0.f;
#pragma unroll
    for (int j = 0; j < 64; ++j) s = fmaf(w[j], att[j], s);
    watt2[t] = s;
  }
}

// ==================== merged degree-count + attcoef1 (one launch) ====================
// Blocks [0,CB) count degrees; blocks [CB, CB+nb16) run attcoef<128>.
// The two halves are mutually independent (both depend only on prep).
// Barriers are per-block; count blocks return before any barrier.

__global__ __launch_bounds__(256) void count_attcoef_kernel(
    const int* __restrict__ dst, int* __restrict__ deg, int E, int CB,
    const float* __restrict__ feat, const float* __restrict__ watt,
    float* __restrict__ a_s, float* __restrict__ a_d, int n) {
  __shared__ float rows[16 * 128];
  __shared__ float wbuf[128 * 16];
  const int tid = threadIdx.x;
  if (blockIdx.x < CB) {
    int i = blockIdx.x * 256 + tid;
    if (i < E) atomicAdd(&deg[dst[i]], 1);
    return;
  }
  const int n0 = (blockIdx.x - CB) * 16;
  if (n0 + 16 <= n) {
    const float4* g = reinterpret_cast<const float4*>(feat + (size_t)n0 * 128);
    float4* l = reinterpret_cast<float4*>(rows);
    for (int i = tid; i < 512; i += 256) l[i] = g[i];
  } else {
    for (int i = tid; i < 16 * 128; i += 256) {
      int r = i >> 7;
      rows[i] = (n0 + r < n) ? feat[(size_t)(n0 + r) * 128 + (i & 127)] : 0.f;
    }
  }
  {
    const float4* g = reinterpret_cast<const float4*>(watt);
    float4* l = reinterpret_cast<float4*>(wbuf);
    for (int i = tid; i < 512; i += 256) l[i] = g[i];
  }
  __syncthreads();
  const int local = tid >> 4, c = tid & 15;
  float s = 0.f;
#pragma unroll 8
  for (int f = 0; f < 128; ++f) s = fmaf(rows[local * 128 + f], wbuf[f * 16 + c], s);
  const int node = n0 + local;
  if (node < n) {
    if (c < 8) a_s[(size_t)node * 8 + c] = s;
    else       a_d[(size_t)node * 8 + (c - 8)] = s;
  }
}

// ==================== attention coefficients (layer-agnostic, kept for F=64 path) ====================

template <int F>
__global__ __launch_bounds__(256) void attcoef_kernel(
    const float* __restrict__ feat, const float* __restrict__ watt,
    float* __restrict__ a_s, float* __restrict__ a_d, int n) {
  __shared__ float rows[16 * F];
  __shared__ float wbuf[F * 16];
  const int n0 = blockIdx.x * 16;
  const int tid = threadIdx.x;
  if (n0 + 16 <= n) {
    const float4* g = reinterpret_cast<const float4*>(feat + (size_t)n0 * F);
    float4* l = reinterpret_cast<float4*>(rows);
    for (int i = tid; i < 16 * F / 4; i += 256) l[i] = g[i];
  } else {
    for (int i = tid; i < 16 * F; i += 256) {
      int r = i / F;
      rows[i] = (n0 + r < n) ? feat[(size_t)(n0 + r) * F + (i - r * F)] : 0.f;
    }
  }
  {
    const float4* g = reinterpret_cast<const float4*>(watt);
    float4* l = reinterpret_cast<float4*>(wbuf);
    for (int i = tid; i < F * 16 / 4; i += 256) l[i] = g[i];
  }
  __syncthreads();
  const int local = tid >> 4, c = tid & 15;
  float s = 0.f;
#pragma unroll 8
  for (int f = 0; f < F; ++f) s = fmaf(rows[local * F + f], wbuf[f * 16 + c], s);
  const int node = n0 + local;
  if (node < n) {
    if (c < 8) a_s[(size_t)node * 8 + c] = s;
    else       a_d[(size_t)node * 8 + (c - 8)] = s;
  }
}

// ==================== GAT pre-aggregation: one WAVE per dst node ====================
// ROUND-3 implementation (fastest measured across 5 variants). Two passes:
// denominator pass (a_s gathers L2-resident), then aggregate pass staging
// alpha in per-wave LDS chunks of 8 edges. Emits hi/lo bf16 planes.

template <int F>
__global__ __launch_bounds__(256) void gat_aggregate_wave(
    const float* __restrict__ feat, const float* __restrict__ a_s,
    const float* __restrict__ a_d, const int* __restrict__ rowptr,
    const int* __restrict__ col, uint16_t* __restrict__ aggH,
    uint16_t* __restrict__ aggL, int n) {
  constexpr int F4 = F / 4;
  constexpr int HPG = (F == 128) ? 4 : 2;
  __shared__ float s_alpha[4][8][8];
  __shared__ int s_cols[4][8];
  const int wid = threadIdx.x >> 6;
  const int lane = threadIdx.x & 63;
  const int node = blockIdx.x * 4 + wid;
  if (node >= n) return;
  const int start = rowptr[node];
  const int deg = rowptr[node + 1] - start;
  const int j = lane >> 3;
  const int h = lane & 7;
  const float adh = a_d[(size_t)node * 8 + h];
  float den = 0.f;
  for (int e = j; e < deg; e += 8) {
    int s = col[start + e];
    float v = a_s[(size_t)s * 8 + h] + adh;
    v = (v > 0.f) ? v : 0.2f * v;
    den += __expf(v);
  }
  den += __shfl_xor(den, 8);
  den += __shfl_xor(den, 16);
  den += __shfl_xor(den, 32);
  const float inv = 1.f / (den + 1e-16f);
  const int f4 = lane & (F4 - 1);
  const int hbase = (lane / F4) * HPG;
  float4 acc0 = make_float4(0.f, 0.f, 0.f, 0.f);
  float4 acc1 = make_float4(0.f, 0.f, 0.f, 0.f);
  float4 acc2 = make_float4(0.f, 0.f, 0.f, 0.f);
  float4 acc3 = make_float4(0.f, 0.f, 0.f, 0.f);
  for (int c0 = 0; c0 < deg; c0 += 8) {
    float aval = 0.f;
    int sj = 0;
    if (c0 + j < deg) {
      sj = col[start + c0 + j];
      float v = a_s[(size_t)sj * 8 + h] + adh;
      v = (v > 0.f) ? v : 0.2f * v;
      aval = __expf(v) * inv;
    }
    s_alpha[wid][j][h] = aval;
    if (h == 0) s_cols[wid][j] = sj;
    __builtin_amdgcn_wave_barrier();
    const int ce = min(8, deg - c0);
    for (int e = 0; e < ce; ++e) {
      int s = s_cols[wid][e];
      float4 fv = *reinterpret_cast<const float4*>(feat + (size_t)s * F + f4 * 4);
      if constexpr (HPG == 4) {
        float4 al = *reinterpret_cast<const float4*>(&s_alpha[wid][e][hbase]);
        acc0.x = fmaf(al.x, fv.x, acc0.x); acc0.y = fmaf(al.x, fv.y, acc0.y);
        acc0.z = fmaf(al.x, fv.z, acc0.z); acc0.w = fmaf(al.x, fv.w, acc0.w);
        acc1.x = fmaf(al.y, fv.x, acc1.x); acc1.y = fmaf(al.y, fv.y, acc1.y);
        acc1.z = fmaf(al.y, fv.z, acc1.z); acc1.w = fmaf(al.y, fv.w, acc1.w);
        acc2.x = fmaf(al.z, fv.x, acc2.x); acc2.y = fmaf(al.z, fv.y, acc2.y);
        acc2.z = fmaf(al.z, fv.z, acc2.z); acc2.w = fmaf(al.z, fv.w, acc2.w);
        acc3.x = fmaf(al.w, fv.x, acc3.x); acc3.y = fmaf(al.w, fv.y, acc3.y);
        acc3.z = fmaf(al.w, fv.z, acc3.z); acc3.w = fmaf(al.w, fv.w, acc3.w);
      } else {
        float2 al = *reinterpret_cast<const float2*>(&s_alpha[wid][e][hbase]);
        acc0.x = fmaf(al.x, fv.x, acc0.x); acc0.y = fmaf(al.x, fv.y, acc0.y);
        acc0.z = fmaf(al.x, fv.z, acc0.z); acc0.w = fmaf(al.x, fv.w, acc0.w);
        acc1.x = fmaf(al.y, fv.x, acc1.x); acc1.y = fmaf(al.y, fv.y, acc1.y);
        acc1.z = fmaf(al.y, fv.z, acc1.z); acc1.w = fmaf(al.y, fv.w, acc1.w);
      }
    }
    __builtin_amdgcn_wave_barrier();
  }
  size_t basep = (size_t)node * 8 * F + (size_t)hbase * F + f4 * 4;
  store4split(aggH + basep, aggL + basep, acc0);
  store4split(aggH + basep + F, aggL + basep + F, acc1);
  if constexpr (HPG == 4) {
    store4split(aggH + basep + 2 * F, aggL + basep + 2 * F, acc2);
    store4split(aggH + basep + 3 * F, aggL + basep + 3 * F, acc3);
  }
}

// ==================== fused LSTM activation + attcoef2 ====================

__global__ __launch_bounds__(256) void lstm_act_attcoef_kernel(
    const float* __restrict__ gates, const float* __restrict__ bsum,
    const float* __restrict__ watt2, float* __restrict__ h2,
    float* __restrict__ a_s2, float* __restrict__ a_d2, int n) {
  __shared__ float h2t[4][64];
  __shared__ float wbuf[64 * 16];
  const int tid = threadIdx.x;
  reinterpret_cast<float4*>(wbuf)[tid] = reinterpret_cast<const float4*>(watt2)[tid];
  const int nl = tid >> 6, j = tid & 63;
  const int node = blockIdx.x * 4 + nl;
  float hv = 0.f;
  if (node < n) {
    const float* g0 = gates + (size_t)node * 192;
    float iv = g0[j] + bsum[j];
    float gv = g0[64 + j] + bsum[64 + j];
    float ov = g0[128 + j] + bsum[128 + j];
    float c = (1.f / (1.f + __expf(-iv))) * tanhf(gv);
    hv = fmaxf((1.f / (1.f + __expf(-ov))) * tanhf(c), 0.f);
    h2[(size_t)node * 64 + j] = hv;
  }
  h2t[nl][j] = hv;
  __syncthreads();
  if (j < 16 && node < n) {
    float s = 0.f;
#pragma unroll 16
    for (int f = 0; f < 64; ++f) s = fmaf(h2t[nl][f], wbuf[f * 16 + j], s);
    if (j < 8) a_s2[(size_t)node * 8 + j] = s;
    else       a_d2[(size_t)node * 8 + (j - 8)] = s;
  }
}

// ==================== fused proj2 + row softmax ====================
// One block = 16 nodes, 8 waves; wave h computes head h (M=16,N=64,K=64) with
// the verified hi/lo MFMA triple (A from agg2 planes in global, B = Bt2,
// L2-resident 128KB). Then block-local softmax over the full 512-wide row:
// wave-level shfl_xor reduce over fr-lanes -> s_red[8][16] -> combine.
// Same max-subtract math as softmax512_wave. No early returns before
// barriers; OOB A-rows clamped (per-row reductions uncontaminated), stores
// guarded. Kills the h3p intermediate (82MB) and one launch.

__global__ __launch_bounds__(512) void proj2_softmax(
    const uint16_t* __restrict__ Ah, const uint16_t* __restrict__ Al,
    const uint16_t* __restrict__ Bh, const uint16_t* __restrict__ Bl,
    const float* __restrict__ bias, float* __restrict__ out, int n) {
  __shared__ float s_red[8][16];
  const int tid = threadIdx.x;
  const int wid = tid >> 6, lane = tid & 63;
  const int nb0 = blockIdx.x * 16;
  const int fr = lane & 15, kg = lane >> 4;
  f32x4 pacc[4] = {};
  const int arow = min(nb0 + fr, n - 1);
  const uint16_t* Arh = Ah + (size_t)arow * 512 + wid * 64;
  const uint16_t* Arl = Al + (size_t)arow * 512 + wid * 64;
#pragma unroll
  for (int ks = 0; ks < 2; ++ks) {
    const int kc = ks * 4 + kg;
    bf16x8 ah = *reinterpret_cast<const bf16x8*>(Arh + kc * 8);
    bf16x8 al = *reinterpret_cast<const bf16x8*>(Arl + kc * 8);
#pragma unroll
    for (int jf = 0; jf < 4; ++jf) {
      const size_t bro = (size_t)(wid * 64 + jf * 16 + fr) * 64 + kc * 8;
      bf16x8 bh = *reinterpret_cast<const bf16x8*>(Bh + bro);
      bf16x8 bl = *reinterpret_cast<const bf16x8*>(Bl + bro);
      pacc[jf] = __builtin_amdgcn_mfma_f32_16x16x32_bf16(ah, bh, pacc[jf], 0, 0, 0);
      pacc[jf] = __builtin_amdgcn_mfma_f32_16x16x32_bf16(al, bh, pacc[jf], 0, 0, 0);
      pacc[jf] = __builtin_amdgcn_mfma_f32_16x16x32_bf16(ah, bl, pacc[jf], 0, 0, 0);
    }
  }
  // v[jf][rr] for output row lr = kg*4+rr, col = wid*64 + jf*16 + fr
  float v[4][4];
#pragma unroll
  for (int jf = 0; jf < 4; ++jf) {
    float bz = bias[wid * 64 + jf * 16 + fr];
#pragma unroll
    for (int rr = 0; rr < 4; ++rr) v[jf][rr] = pacc[jf][rr] + bz;
  }
  // wave-level per-row max (over jf, then fr lanes: bits 0..3)
  float lm[4];
#pragma unroll
  for (int rr = 0; rr < 4; ++rr) {
    float m = fmaxf(fmaxf(v[0][rr], v[1][rr]), fmaxf(v[2][rr], v[3][rr]));
#pragma unroll
    for (int d = 1; d < 16; d <<= 1) m = fmaxf(m, __shfl_xor(m, d));
    lm[rr] = m;
  }
  if (fr == 0) {
#pragma unroll
    for (int rr = 0; rr < 4; ++rr) s_red[wid][kg * 4 + rr] = lm[rr];
  }
  __syncthreads();
  float gm[4];
#pragma unroll
  for (int rr = 0; rr < 4; ++rr) {
    int lr = kg * 4 + rr;
    float m = s_red[0][lr];
#pragma unroll
    for (int w = 1; w < 8; ++w) m = fmaxf(m, s_red[w][lr]);
    gm[rr] = m;
  }
  __syncthreads();  // all reads of maxes done before s_red is reused for sums
  float ls[4] = {0.f, 0.f, 0.f, 0.f};
#pragma unroll
  for (int jf = 0; jf < 4; ++jf)
#pragma unroll
    for (int rr = 0; rr < 4; ++rr) {
      v[jf][rr] = __expf(v[jf][rr] - gm[rr]);
      ls[rr] += v[jf][rr];
    }
#pragma unroll
  for (int rr = 0; rr < 4; ++rr) {
#pragma unroll
    for (int d = 1; d < 16; d <<= 1) ls[rr] += __shfl_xor(ls[rr], d);
  }
  if (fr == 0) {
#pragma unroll
    for (int rr = 0; rr < 4; ++rr) s_red[wid][kg * 4 + rr] = ls[rr];
  }
  __syncthreads();
#pragma unroll
  for (int rr = 0; rr < 4; ++rr) {
    int lr = kg * 4 + rr;
    float s = 0.f;
#pragma unroll
    for (int w = 0; w < 8; ++w) s += s_red[w][lr];
    float inv = 1.f / s;
    int m = nb0 + lr;
    if (m < n) {
#pragma unroll
      for (int jf = 0; jf < 4; ++jf)
        out[(size_t)m * 512 + wid * 64 + jf * 16 + fr] = v[jf][rr] * inv;
    }
  }
}

// ============================ launch ============================

extern "C" void kernel_launch(void* const* d_in, const int* in_sizes, int n_in,
                              void* d_out, int out_size, void* d_ws, size_t ws_size,
                              hipStream_t stream) {
  const float* x      = (const float*)d_in[0];
  const int*   ei     = (const int*)d_in[1];
  const float* W1     = (const float*)d_in[3];
  const float* att_s1 = (const float*)d_in[4];
  const float* att_d1 = (const float*)d_in[5];
  const float* bias1  = (const float*)d_in[6];
  const float* W_ih   = (const float*)d_in[7];
  const float* b_ih   = (const float*)d_in[9];
  const float* b_hh   = (const float*)d_in[10];
  const float* W2     = (const float*)d_in[11];
  const float* att_s2 = (const float*)d_in[12];
  const float* att_d2 = (const float*)d_in[13];
  const float* bias2  = (const float*)d_in[14];
  float* out = (float*)d_out;

  const int N = in_sizes[0] / 128;
  const int E = in_sizes[1] / 2;
  const int* src = ei;
  const int* dst = ei + E;

  char* p = (char*)d_ws;
  auto alloc = [&](size_t bytes) {
    char* r = p;
    p += (bytes + 255) & ~(size_t)255;
    return r;
  };
  char* slotA = alloc((size_t)N * 4096);  // agg1 planes; later gates2+h2+agg2 planes
  char* slotB = alloc((size_t)N * 2048);  // g1 planes
  float* a_s1 = (float*)alloc((size_t)N * 8 * 4);
  float* a_d1 = (float*)alloc((size_t)N * 8 * 4);
  float* a_s2 = (float*)alloc((size_t)N * 8 * 4);
  float* a_d2 = (float*)alloc((size_t)N * 8 * 4);
  float* watt1 = (float*)alloc(128 * 16 * 4);
  float* watt2 = (float*)alloc(64 * 16 * 4);
  uint16_t* Wtbh = (uint16_t*)alloc((size_t)192 * 512 * 2);
  uint16_t* Wtbl = (uint16_t*)alloc((size_t)192 * 512 * 2);
  uint16_t* Bt1h = (uint16_t*)alloc((size_t)512 * 128 * 2);
  uint16_t* Bt1l = (uint16_t*)alloc((size_t)512 * 128 * 2);
  uint16_t* Bt2h = (uint16_t*)alloc((size_t)512 * 64 * 2);
  uint16_t* Bt2l = (uint16_t*)alloc((size_t)512 * 64 * 2);
  float* bsum = (float*)alloc(192 * 4);
  int* deg    = (int*)alloc((size_t)2 * N * 4);  // deg + wp adjacent
  int* wp     = deg + N;
  int* rowptr = (int*)alloc((size_t)(N + 1) * 4);
  int* col    = (int*)alloc((size_t)(E + N) * 4);

  // slotA phase 1: agg1 hi/lo planes [N,1024] bf16 each
  uint16_t* agg1h = (uint16_t*)slotA;
  uint16_t* agg1l = agg1h + (size_t)N * 1024;
  // slotA phase 2 (agg1 dead after proj1): gates2 [N,192] f32, h2 [N,64] f32,
  // agg2 hi/lo planes [N,512] bf16 each  (768 + 256 + 1024 + 1024 <= 4096 B/node)
  float* gates2 = (float*)slotA;
  float* h2 = (float*)(slotA + (size_t)N * 768);
  uint16_t* agg2h = (uint16_t*)(slotA + (size_t)N * 1024);
  uint16_t* agg2l = agg2h + (size_t)N * 512;
  // slotB: g1 hi/lo planes [N,512] bf16 each
  uint16_t* g1h = (uint16_t*)slotB;
  uint16_t* g1l = g1h + (size_t)N * 512;

  // ---- merged prep (also zeroes deg/wp) ----
  {
    int total = 2 * N + 98304 + 65536 + 32768 + 192 + 2048 + 1024;
    prep_all_kernel<<<(total + 255) / 256, 256, 0, stream>>>(
        W_ih, b_ih, b_hh, W1, att_s1, att_d1, W2, att_s2, att_d2,
        deg, Wtbh, Wtbl, Bt1h, Bt1l, Bt2h, Bt2l, bsum, watt1, watt2, 2 * N);
  }

  // ---- degree count + attcoef1 (merged, independent halves) ----
  {
    const int CB = (E + 255) / 256;
    const int AB = (N + 15) / 16;
    count_attcoef_kernel<<<CB + AB, 256, 0, stream>>>(
        dst, deg, E, CB, x, watt1, a_s1, a_d1, N);
  }
  scan_kernel<<<1, 1024, 0, stream>>>(deg, rowptr, N);
  scatter_kernel<<<(E + N + 255) / 256, 256, 0, stream>>>(src, dst, rowptr, wp, col, E, N);

  const int NYB = (N + 63) / 64;

  // ---- GATConv1: aggregate x (emit split planes), project ----
  gat_aggregate_wave<128><<<(N + 3) / 4, 256, 0, stream>>>(x, a_s1, a_d1, rowptr, col,
                                                           agg1h, agg1l, N);
  {
    dim3 g(1, NYB, 8);
    gemm_mfma<true><<<g, 256, 0, stream>>>(
        agg1h, agg1l, Bt1h, Bt1l, nullptr, g1h, g1l, bias1,
        N, 128, /*lda*/1024, /*aZ*/128, /*bZ*/64 * 128, /*ldc*/512, /*cZ*/64, /*biasZ*/64);
  }

  // ---- LSTM gates GEMM + fused act/attcoef2 ----
  {
    dim3 g(3, NYB, 1);
    gemm_mfma<false><<<g, 256, 0, stream>>>(
        g1h, g1l, Wtbh, Wtbl, gates2, nullptr, nullptr, nullptr,
        N, 512, /*lda*/512, 0, 0, /*ldc*/192, 0, 0);
  }
  lstm_act_attcoef_kernel<<<(N + 3) / 4, 256, 0, stream>>>(gates2, bsum, watt2,
                                                           h2, a_s2, a_d2, N);

  // ---- GATConv2: aggregate h2 (emit split planes), project + softmax fused ----
  gat_aggregate_wave<64><<<(N + 3) / 4, 256, 0, stream>>>(h2, a_s2, a_d2, rowptr, col,
                                                          agg2h, agg2l, N);
  proj2_softmax<<<(N + 15) / 16, 512, 0, stream>>>(agg2h, agg2l, Bt2h, Bt2l,
                                                   bias2, out, N);
}